// Round 5
// baseline (108.559 us; speedup 1.0000x reference)
//
#include <hip/hip_runtime.h>
#include <math.h>

// x: (32,32,32,32) f32; 6 layers, O=64 trees, gates/layer = 32,16,8,4,2,1
// out: (32,64,32,32) f32
//
// Fused-expansion formulation: the root gate's dependency cone, expanded as a
// binary tree, has exactly 63 nodes (1+2+4+8+16+32) == total gates per tree.
// Precompute the expanded tree (coefs duplicated per expansion node, gates
// consumed 0x dropped) -> evaluation has ONLY static indices:
//   t1[n] = gate(t0[2n], t0[2n+1]).  No scratch, no readlane, no dyn extract.
//
// Per-tree table (288 dwords, 16B aligned):
//   [0..31]   packed leaf slab offsets (offa | offb<<16) for L0 node n
//   [32..283] float4 coefs, node slots: L0 n->n, L1 n->32+n, L2->48+n,
//             L3->56+n, L4->60+n, L5->62

struct Tabs { const int* ia[6]; const int* ib[6]; const float* w[6]; };

__device__ __constant__ float GM[64] = {
  0,0,0,0,   0,0,0,1,   0,1,0,-1,  0,1,0,0,
  0,0,1,-1,  0,0,1,0,   0,1,1,-2,  0,1,1,-1,
  1,-1,-1,1, 1,-1,-1,2, 1,0,-1,0,  1,0,-1,1,
  1,-1,0,0,  1,-1,0,1,  1,0,0,-1,  1,0,0,0 };

// y = c0 + c1*a + c2*b + c3*a*b  ==  fma(c2,b, fma(a, fma(c3,b,c1), c0))
#define GATE4(a, b, c0, c1, c2, c3) \
  fmaf((c2), (b), fmaf((a), fmaf((c3), (b), (c1)), (c0)))

__global__ __launch_bounds__(64) void build_tree(Tabs t, unsigned* __restrict tab) {
  const int o = threadIdx.x;
  if (o >= 64) return;

  // walk expansion top-down: gate id at each (level, slot)
  int g4[2], g3[4], g2[8], g1[16], g0[32];
  g4[0] = t.ia[5][o];            // (O,1) -> index into L4's 2 gates
  g4[1] = t.ib[5][o];
  for (int s = 0; s < 4;  ++s) { int gp = g4[s >> 1];
    g3[s] = ((s & 1) ? t.ib[4] : t.ia[4])[o * 2  + gp]; }   // (O,2), vals [0,4)
  for (int s = 0; s < 8;  ++s) { int gp = g3[s >> 1];
    g2[s] = ((s & 1) ? t.ib[3] : t.ia[3])[o * 4  + gp]; }   // (O,4), vals [0,8)
  for (int s = 0; s < 16; ++s) { int gp = g2[s >> 1];
    g1[s] = ((s & 1) ? t.ib[2] : t.ia[2])[o * 8  + gp]; }   // (O,8), vals [0,16)
  for (int s = 0; s < 32; ++s) { int gp = g1[s >> 1];
    g0[s] = ((s & 1) ? t.ib[1] : t.ia[1])[o * 16 + gp]; }   // (O,16), vals [0,32)

  unsigned* T = tab + o * 288;

  // leaves: slab offsets for L0 node n (slab xr[c][4][34], lane adds rbase*34+j)
  for (int n = 0; n < 32; ++n) {
    int g  = g0[n];
    int ia = t.ia[0][o * 32 + g], ib = t.ib[0][o * 32 + g]; // vals [0,288)
    int ca = ia / 9, ra = ia - ca * 9, kia = ra / 3, kja = ra - kia * 3;
    int cb = ib / 9, rb = ib - cb * 9, kib = rb / 3, kjb = rb - kib * 3;
    unsigned offa = (unsigned)((ca * 4 + kia) * 34 + kja);
    unsigned offb = (unsigned)((cb * 4 + kib) * 34 + kjb);
    T[n] = offa | (offb << 16);
  }

  float4* C = (float4*)(T + 32);
  const int dl[6] = {32, 16, 8, 4, 2, 1};
  auto emit = [&](int slot, int l, int g) {
    const float* wp = t.w[l] + (o * dl[l] + g) * 16;
    float wv[16]; float m = -1e30f;
    #pragma unroll
    for (int k = 0; k < 16; ++k) { wv[k] = wp[k]; m = fmaxf(m, wv[k]); }
    float e[16], s = 0.f;
    #pragma unroll
    for (int k = 0; k < 16; ++k) { e[k] = expf(wv[k] - m); s += e[k]; }
    float inv = 1.0f / s;
    float c0 = 0, c1 = 0, c2 = 0, c3 = 0;
    #pragma unroll
    for (int k = 0; k < 16; ++k) {
      float p = e[k] * inv;
      c0 += p * GM[k*4+0]; c1 += p * GM[k*4+1];
      c2 += p * GM[k*4+2]; c3 += p * GM[k*4+3];
    }
    float4 c; c.x = c0; c.y = c1; c.z = c2; c.w = c3;
    C[slot] = c;
  };
  for (int n = 0; n < 32; ++n) emit(n,      0, g0[n]);
  for (int n = 0; n < 16; ++n) emit(32 + n, 1, g1[n]);
  for (int n = 0; n < 8;  ++n) emit(48 + n, 2, g2[n]);
  for (int n = 0; n < 4;  ++n) emit(56 + n, 3, g3[n]);
  for (int n = 0; n < 2;  ++n) emit(60 + n, 4, g4[n]);
  emit(62, 5, 0);
}

// Block: 256 threads = 4 waves; each wave = 64 px (2 rows x 32 cols), 4 trees.
// bid bits: [1:0]=treechunk(16 trees), [5:2]=rowchunk(2 rows), [10:6]=batch
// LDS = slab only (17 KiB) -> 8 blocks/CU resident, 32 waves/CU.
__global__ __launch_bounds__(256) void logic_conv(const float* __restrict x,
                                                  const unsigned* __restrict tab,
                                                  float* __restrict out) {
  __shared__ float xr[4352];                     // 32ch * 4rows * 34cols
  const int bid = blockIdx.x;
  const int tc = bid & 3, rc = (bid >> 2) & 15, b = bid >> 6;
  const int r0 = rc * 2;
  const int tid = threadIdx.x;

  // stage input slab: rows r0-1 .. r0+2, cols -1..32, zero-padded OOB
  for (int idx = tid; idx < 4352; idx += 256) {
    int c = idx / 136, rem = idx - c * 136;
    int rr = rem / 34, sc = rem - rr * 34;
    int gr = r0 - 1 + rr, gc = sc - 1;
    float v = 0.f;
    if ((unsigned)gr < 32u && (unsigned)gc < 32u)
      v = x[((b * 32 + c) * 32 + gr) * 32 + gc];
    xr[idx] = v;
  }
  __syncthreads();

  const int th = tid >> 6;           // 0..3: wave id -> tree subset
  const int rbase = (tid >> 5) & 1;  // relative output row
  const int j = tid & 31;            // output col
  const int lbase = rbase * 34 + j;
  const int o0 = tc * 16 + th * 4;   // first tree for this wave
  float* outb = out + ((b * 64 + o0) * 32 + (r0 + rbase)) * 32 + j;

  for (int t = 0; t < 4; ++t) {
    const int o = __builtin_amdgcn_readfirstlane(o0 + t);   // uniform -> s_load path
    const unsigned* __restrict T = tab + o * 288;
    const float4*  __restrict C = (const float4*)(T + 32);

    float t0[32];
    #pragma unroll
    for (int n = 0; n < 32; ++n) {
      unsigned ip = T[n];
      float4 c = C[n];
      float a  = xr[(ip & 0xffffu) + lbase];
      float bb = xr[(ip >> 16) + lbase];
      t0[n] = GATE4(a, bb, c.x, c.y, c.z, c.w);
    }
    float t1[16];
    #pragma unroll
    for (int n = 0; n < 16; ++n) {
      float4 c = C[32 + n];
      t1[n] = GATE4(t0[2*n], t0[2*n+1], c.x, c.y, c.z, c.w);
    }
    float t2[8];
    #pragma unroll
    for (int n = 0; n < 8; ++n) {
      float4 c = C[48 + n];
      t2[n] = GATE4(t1[2*n], t1[2*n+1], c.x, c.y, c.z, c.w);
    }
    float t3[4];
    #pragma unroll
    for (int n = 0; n < 4; ++n) {
      float4 c = C[56 + n];
      t3[n] = GATE4(t2[2*n], t2[2*n+1], c.x, c.y, c.z, c.w);
    }
    float t4[2];
    #pragma unroll
    for (int n = 0; n < 2; ++n) {
      float4 c = C[60 + n];
      t4[n] = GATE4(t3[2*n], t3[2*n+1], c.x, c.y, c.z, c.w);
    }
    {
      float4 c = C[62];
      outb[0] = GATE4(t4[0], t4[1], c.x, c.y, c.z, c.w);
    }
    outb += 1024;                    // next tree: +32*32
  }
}

extern "C" void kernel_launch(void* const* d_in, const int* in_sizes, int n_in,
                              void* d_out, int out_size, void* d_ws, size_t ws_size,
                              hipStream_t stream) {
  const float* x = (const float*)d_in[0];
  Tabs tabs;
  for (int l = 0; l < 6; ++l) {
    tabs.ia[l] = (const int*)d_in[1 + 3 * l];
    tabs.ib[l] = (const int*)d_in[2 + 3 * l];
    tabs.w[l]  = (const float*)d_in[3 + 3 * l];
  }
  unsigned* tab = (unsigned*)d_ws;              // 64 trees * 288 dw = 73.7 KB
  build_tree<<<1, 64, 0, stream>>>(tabs, tab);
  logic_conv<<<2048, 256, 0, stream>>>(x, tab, (float*)d_out);
}

// Round 6
// 52.490 us; speedup vs baseline: 2.0682x; 2.0682x over previous
//
#include <hip/hip_runtime.h>
#include <math.h>

// x: (32,32,32,32) f32; 6 layers, O=64 trees, gates/layer = 32,16,8,4,2,1
// out: (32,64,32,32) f32
//
// Fused-expansion formulation: the root gate's dependency cone, expanded as a
// binary tree, has exactly 63 nodes (1+2+4+8+16+32) == total gates per tree.
// Precompute the expanded tree (coefs duplicated per expansion node, gates
// consumed 0x dropped) -> evaluation has ONLY static indices:
//   t1[n] = gate(t0[2n], t0[2n+1]).  No scratch, no readlane, no dyn extract.
//
// d_ws layout (dwords):
//   tab[o*288 + 0..31]    packed leaf slab offsets (offa | offb<<16), L0 node n
//   tab[o*288 + 32..283]  float4 coefs, slots: L0 n->n, L1->32+n, L2->48+n,
//                         L3->56+n, L4->60+n, L5->62
//   map = tab + 64*288;  map[o*64 + slot] = original gate id for that node

struct Tabs { const int* ia[6]; const int* ib[6]; const float* w[6]; };

__device__ __constant__ float GM[64] = {
  0,0,0,0,   0,0,0,1,   0,1,0,-1,  0,1,0,0,
  0,0,1,-1,  0,0,1,0,   0,1,1,-2,  0,1,1,-1,
  1,-1,-1,1, 1,-1,-1,2, 1,0,-1,0,  1,0,-1,1,
  1,-1,0,0,  1,-1,0,1,  1,0,0,-1,  1,0,0,0 };

// y = c0 + c1*a + c2*b + c3*a*b  ==  fma(c2,b, fma(a, fma(c3,b,c1), c0))
#define GATE4(a, b, c0, c1, c2, c3) \
  fmaf((c2), (b), fmaf((a), fmaf((c3), (b), (c1)), (c0)))

// ---- builder A: topology walk (cheap, 64 threads) ----
__global__ __launch_bounds__(64) void build_topo(Tabs t, unsigned* __restrict tab) {
  const int o = threadIdx.x;
  if (o >= 64) return;

  int g4[2], g3[4], g2[8], g1[16], g0[32];
  g4[0] = t.ia[5][o];
  g4[1] = t.ib[5][o];
  for (int s = 0; s < 4;  ++s) { int gp = g4[s >> 1];
    g3[s] = ((s & 1) ? t.ib[4] : t.ia[4])[o * 2  + gp]; }
  for (int s = 0; s < 8;  ++s) { int gp = g3[s >> 1];
    g2[s] = ((s & 1) ? t.ib[3] : t.ia[3])[o * 4  + gp]; }
  for (int s = 0; s < 16; ++s) { int gp = g2[s >> 1];
    g1[s] = ((s & 1) ? t.ib[2] : t.ia[2])[o * 8  + gp]; }
  for (int s = 0; s < 32; ++s) { int gp = g1[s >> 1];
    g0[s] = ((s & 1) ? t.ib[1] : t.ia[1])[o * 16 + gp]; }

  unsigned* T = tab + o * 288;
  // leaves: slab offsets for L0 node n (slab xr[c][4][34], lane adds rbase*34+j)
  for (int n = 0; n < 32; ++n) {
    int g  = g0[n];
    int ia = t.ia[0][o * 32 + g], ib = t.ib[0][o * 32 + g];
    int ca = ia / 9, ra = ia - ca * 9, kia = ra / 3, kja = ra - kia * 3;
    int cb = ib / 9, rb = ib - cb * 9, kib = rb / 3, kjb = rb - kib * 3;
    unsigned offa = (unsigned)((ca * 4 + kia) * 34 + kja);
    unsigned offb = (unsigned)((cb * 4 + kib) * 34 + kjb);
    T[n] = offa | (offb << 16);
  }

  unsigned* map = tab + 64 * 288 + o * 64;
  for (int n = 0; n < 32; ++n) map[n]      = (unsigned)g0[n];
  for (int n = 0; n < 16; ++n) map[32 + n] = (unsigned)g1[n];
  for (int n = 0; n < 8;  ++n) map[48 + n] = (unsigned)g2[n];
  for (int n = 0; n < 4;  ++n) map[56 + n] = (unsigned)g3[n];
  for (int n = 0; n < 2;  ++n) map[60 + n] = (unsigned)g4[n];
  map[62] = 0;
  map[63] = 0;
}

// ---- builder B: one softmax per expanded node (4096 threads) ----
__global__ __launch_bounds__(256) void emit_coefs(Tabs t, unsigned* __restrict tab) {
  const int gid = blockIdx.x * 256 + threadIdx.x;     // [0, 4096)
  const int o = gid >> 6, slot = gid & 63;
  if (slot >= 63) return;
  int l;
  if      (slot < 32) l = 0;
  else if (slot < 48) l = 1;
  else if (slot < 56) l = 2;
  else if (slot < 60) l = 3;
  else if (slot < 62) l = 4;
  else                l = 5;
  const int dl[6] = {32, 16, 8, 4, 2, 1};
  const unsigned* map = tab + 64 * 288;
  int g = (int)map[o * 64 + slot];

  const float4* wp = (const float4*)(t.w[l] + (o * dl[l] + g) * 16);
  float4 w0 = wp[0], w1 = wp[1], w2 = wp[2], w3 = wp[3];
  float wv[16] = { w0.x,w0.y,w0.z,w0.w, w1.x,w1.y,w1.z,w1.w,
                   w2.x,w2.y,w2.z,w2.w, w3.x,w3.y,w3.z,w3.w };
  float m = -1e30f;
  #pragma unroll
  for (int k = 0; k < 16; ++k) m = fmaxf(m, wv[k]);
  float e[16], s = 0.f;
  #pragma unroll
  for (int k = 0; k < 16; ++k) { e[k] = expf(wv[k] - m); s += e[k]; }
  float inv = 1.0f / s;
  float c0 = 0, c1 = 0, c2 = 0, c3 = 0;
  #pragma unroll
  for (int k = 0; k < 16; ++k) {
    float p = e[k] * inv;
    c0 += p * GM[k*4+0]; c1 += p * GM[k*4+1];
    c2 += p * GM[k*4+2]; c3 += p * GM[k*4+3];
  }
  float4* C = (float4*)(tab + o * 288 + 32);
  float4 c; c.x = c0; c.y = c1; c.z = c2; c.w = c3;
  C[slot] = c;
}

// Block: 256 threads = 4 waves; each wave = 64 px (2 rows x 32 cols), 4 trees.
// bid bits: [1:0]=treechunk(16 trees), [5:2]=rowchunk(2 rows), [10:6]=batch
// LDS = slab only (17 KiB) -> 8 blocks/CU resident, 32 waves/CU.
__global__ __launch_bounds__(256) void logic_conv(const float* __restrict x,
                                                  const unsigned* __restrict tab,
                                                  float* __restrict out) {
  __shared__ float xr[4352];                     // 32ch * 4rows * 34cols
  const int bid = blockIdx.x;
  const int tc = bid & 3, rc = (bid >> 2) & 15, b = bid >> 6;
  const int r0 = rc * 2;
  const int tid = threadIdx.x;

  for (int idx = tid; idx < 4352; idx += 256) {
    int c = idx / 136, rem = idx - c * 136;
    int rr = rem / 34, sc = rem - rr * 34;
    int gr = r0 - 1 + rr, gc = sc - 1;
    float v = 0.f;
    if ((unsigned)gr < 32u && (unsigned)gc < 32u)
      v = x[((b * 32 + c) * 32 + gr) * 32 + gc];
    xr[idx] = v;
  }
  __syncthreads();

  const int th = tid >> 6;           // 0..3: wave id -> tree subset
  const int rbase = (tid >> 5) & 1;  // relative output row
  const int j = tid & 31;            // output col
  const int lbase = rbase * 34 + j;
  const int o0 = tc * 16 + th * 4;   // first tree for this wave
  float* outb = out + ((b * 64 + o0) * 32 + (r0 + rbase)) * 32 + j;

  for (int t = 0; t < 4; ++t) {
    const int o = __builtin_amdgcn_readfirstlane(o0 + t);   // uniform -> s_load path
    const unsigned* __restrict T = tab + o * 288;
    const float4*  __restrict C = (const float4*)(T + 32);

    float t0[32];
    #pragma unroll
    for (int n = 0; n < 32; ++n) {
      unsigned ip = T[n];
      float4 c = C[n];
      float a  = xr[(ip & 0xffffu) + lbase];
      float bb = xr[(ip >> 16) + lbase];
      t0[n] = GATE4(a, bb, c.x, c.y, c.z, c.w);
    }
    float t1[16];
    #pragma unroll
    for (int n = 0; n < 16; ++n) {
      float4 c = C[32 + n];
      t1[n] = GATE4(t0[2*n], t0[2*n+1], c.x, c.y, c.z, c.w);
    }
    float t2[8];
    #pragma unroll
    for (int n = 0; n < 8; ++n) {
      float4 c = C[48 + n];
      t2[n] = GATE4(t1[2*n], t1[2*n+1], c.x, c.y, c.z, c.w);
    }
    float t3[4];
    #pragma unroll
    for (int n = 0; n < 4; ++n) {
      float4 c = C[56 + n];
      t3[n] = GATE4(t2[2*n], t2[2*n+1], c.x, c.y, c.z, c.w);
    }
    float t4[2];
    #pragma unroll
    for (int n = 0; n < 2; ++n) {
      float4 c = C[60 + n];
      t4[n] = GATE4(t3[2*n], t3[2*n+1], c.x, c.y, c.z, c.w);
    }
    {
      float4 c = C[62];
      outb[0] = GATE4(t4[0], t4[1], c.x, c.y, c.z, c.w);
    }
    outb += 1024;                    // next tree: +32*32
  }
}

extern "C" void kernel_launch(void* const* d_in, const int* in_sizes, int n_in,
                              void* d_out, int out_size, void* d_ws, size_t ws_size,
                              hipStream_t stream) {
  const float* x = (const float*)d_in[0];
  Tabs tabs;
  for (int l = 0; l < 6; ++l) {
    tabs.ia[l] = (const int*)d_in[1 + 3 * l];
    tabs.ib[l] = (const int*)d_in[2 + 3 * l];
    tabs.w[l]  = (const float*)d_in[3 + 3 * l];
  }
  unsigned* tab = (unsigned*)d_ws;   // 64*288 dw table + 64*64 dw map = 90 KB
  build_topo<<<1, 64, 0, stream>>>(tabs, tab);
  emit_coefs<<<16, 256, 0, stream>>>(tabs, tab);
  logic_conv<<<2048, 256, 0, stream>>>(x, tab, (float*)d_out);
}

// Round 7
// 37.611 us; speedup vs baseline: 2.8864x; 1.3956x over previous
//
#include <hip/hip_runtime.h>
#include <math.h>

// x: (32,32,32,32) f32; 6 layers, O=64 trees, gates/layer = 32,16,8,4,2,1
// out: (32,64,32,32) f32
//
// Fused-expansion formulation: the root gate's dependency cone, expanded as a
// binary tree, has exactly 63 nodes (1+2+4+8+16+32) == total gates per tree.
// Precompute the expanded tree (coefs duplicated per expansion node) ->
// evaluation has ONLY static indices: t1[n] = gate(t0[2n], t0[2n+1]).
//
// d_ws layout (dwords), per tree o (288 dwords, 16B aligned):
//   tab[o*288 + 0..31]    packed leaf slab offsets (offa | offb<<16), L0 node n
//   tab[o*288 + 32..283]  float4 coefs, slots: L0 n->n, L1->32+n, L2->48+n,
//                         L3->56+n, L4->60+n, L5->62

struct Tabs { const int* ia[6]; const int* ib[6]; const float* w[6]; };

__device__ __constant__ float GM[64] = {
  0,0,0,0,   0,0,0,1,   0,1,0,-1,  0,1,0,0,
  0,0,1,-1,  0,0,1,0,   0,1,1,-2,  0,1,1,-1,
  1,-1,-1,1, 1,-1,-1,2, 1,0,-1,0,  1,0,-1,1,
  1,-1,0,0,  1,-1,0,1,  1,0,0,-1,  1,0,0,0 };

// y = c0 + c1*a + c2*b + c3*a*b  ==  fma(c2,b, fma(a, fma(c3,b,c1), c0))
#define GATE4(a, b, c0, c1, c2, c3) \
  fmaf((c2), (b), fmaf((a), fmaf((c3), (b), (c1)), (c0)))

// ---- builder: one thread per expanded node; walks its own root->node path ----
__global__ __launch_bounds__(256) void build_tree(Tabs t, unsigned* __restrict tab) {
  const int gid = blockIdx.x * 256 + threadIdx.x;     // [0, 4096)
  const int o = gid >> 6, slot = gid & 63;
  if (slot >= 63) return;
  int L, m;
  if      (slot < 32) { L = 0; m = slot;      }
  else if (slot < 48) { L = 1; m = slot - 32; }
  else if (slot < 56) { L = 2; m = slot - 48; }
  else if (slot < 60) { L = 3; m = slot - 56; }
  else if (slot < 62) { L = 4; m = slot - 60; }
  else                { L = 5; m = 0;         }
  const int dcnt[6] = {32, 16, 8, 4, 2, 1};
  const int d = 5 - L;                 // path length from root
  int g = 0;                           // gate id at current level (root = gate 0)
  for (int step = 0; step < d; ++step) {
    int lyr = 5 - step;
    int bit = (m >> (d - 1 - step)) & 1;
    g = (bit ? t.ib[lyr] : t.ia[lyr])[o * dcnt[lyr] + g];
  }

  // coefficients: softmax(w[L][o, g]) @ GATE_M
  const float4* wp = (const float4*)(t.w[L] + (o * dcnt[L] + g) * 16);
  float4 w0 = wp[0], w1 = wp[1], w2 = wp[2], w3 = wp[3];
  float wv[16] = { w0.x,w0.y,w0.z,w0.w, w1.x,w1.y,w1.z,w1.w,
                   w2.x,w2.y,w2.z,w2.w, w3.x,w3.y,w3.z,w3.w };
  float mx = -1e30f;
  #pragma unroll
  for (int k = 0; k < 16; ++k) mx = fmaxf(mx, wv[k]);
  float e[16], s = 0.f;
  #pragma unroll
  for (int k = 0; k < 16; ++k) { e[k] = expf(wv[k] - mx); s += e[k]; }
  float inv = 1.0f / s;
  float c0 = 0, c1 = 0, c2 = 0, c3 = 0;
  #pragma unroll
  for (int k = 0; k < 16; ++k) {
    float p = e[k] * inv;
    c0 += p * GM[k*4+0]; c1 += p * GM[k*4+1];
    c2 += p * GM[k*4+2]; c3 += p * GM[k*4+3];
  }
  float4* C = (float4*)(tab + o * 288 + 32);
  float4 c; c.x = c0; c.y = c1; c.z = c2; c.w = c3;
  C[slot] = c;

  if (L == 0) {
    // leaf slab offsets: feature f = ch*9 + ki*3 + kj -> xr[ch][6][34] offset
    int ia = t.ia[0][o * 32 + g], ib = t.ib[0][o * 32 + g];
    int ca = ia / 9, ra = ia - ca * 9, kia = ra / 3, kja = ra - kia * 3;
    int cb = ib / 9, rb = ib - cb * 9, kib = rb / 3, kjb = rb - kib * 3;
    unsigned offa = (unsigned)((ca * 6 + kia) * 34 + kja);
    unsigned offb = (unsigned)((cb * 6 + kib) * 34 + kjb);
    tab[o * 288 + slot] = offa | (offb << 16);
  }
}

// Block: 256 threads = 4 waves; block covers 4 rows x 32 cols = 128 px.
// Each lane owns 2 adjacent columns (cols 2c, 2c+1) -> ds_read2_b32 leaf reads,
// dwordx2 stores, 2x ILP on the serial gate chains. Each wave does 4 trees
// over the full 128 px.
// bid bits: [1:0]=treechunk(16 trees), [4:2]=rowchunk(4 rows), [9:5]=batch
// LDS slab 32ch x 6rows x 34cols = 25.5 KiB -> 4 blocks/CU resident (grid 1024).
__global__ __launch_bounds__(256) void logic_conv(const float* __restrict x,
                                                  const unsigned* __restrict tab,
                                                  float* __restrict out) {
  __shared__ float xr[6528];                     // 32ch * 6rows * 34cols
  const int bid = blockIdx.x;
  const int tc = bid & 3, rc = (bid >> 2) & 7, b = bid >> 5;
  const int r0 = rc * 4;
  const int tid = threadIdx.x;

  // stage input slab: rows r0-1 .. r0+4, cols -1..32, zero-padded OOB
  for (int idx = tid; idx < 6528; idx += 256) {
    int c = idx / 204, rem = idx - c * 204;
    int rr = rem / 34, sc = rem - rr * 34;
    int gr = r0 - 1 + rr, gc = sc - 1;
    float v = 0.f;
    if ((unsigned)gr < 32u && (unsigned)gc < 32u)
      v = x[((b * 32 + c) * 32 + gr) * 32 + gc];
    xr[idx] = v;
  }
  __syncthreads();

  const int th = tid >> 6;             // wave id 0..3 -> tree subset
  const int lane = tid & 63;
  const int rbase = lane >> 4;         // 0..3 relative output row
  const int j = (lane & 15) * 2;       // 0,2,..,30 (col pair)
  const int lbase = rbase * 34 + j;
  const int o0 = tc * 16 + th * 4;     // first tree for this wave
  float* outb = out + ((b * 64 + o0) * 32 + (r0 + rbase)) * 32 + j;

  for (int t = 0; t < 4; ++t) {
    const int o = __builtin_amdgcn_readfirstlane(o0 + t);   // uniform -> s_load
    const unsigned* __restrict T = tab + o * 288;
    const float4*  __restrict C = (const float4*)(T + 32);

    float2 t0[32];
    #pragma unroll
    for (int n = 0; n < 32; ++n) {
      unsigned ip = T[n];
      float4 c = C[n];
      int oa = (int)(ip & 0xffffu) + lbase;
      int ob = (int)(ip >> 16) + lbase;
      float a0 = xr[oa], a1 = xr[oa + 1];        // -> ds_read2_b32
      float b0 = xr[ob], b1 = xr[ob + 1];        // -> ds_read2_b32
      t0[n].x = GATE4(a0, b0, c.x, c.y, c.z, c.w);
      t0[n].y = GATE4(a1, b1, c.x, c.y, c.z, c.w);
    }
    float2 t1[16];
    #pragma unroll
    for (int n = 0; n < 16; ++n) {
      float4 c = C[32 + n];
      t1[n].x = GATE4(t0[2*n].x, t0[2*n+1].x, c.x, c.y, c.z, c.w);
      t1[n].y = GATE4(t0[2*n].y, t0[2*n+1].y, c.x, c.y, c.z, c.w);
    }
    float2 t2[8];
    #pragma unroll
    for (int n = 0; n < 8; ++n) {
      float4 c = C[48 + n];
      t2[n].x = GATE4(t1[2*n].x, t1[2*n+1].x, c.x, c.y, c.z, c.w);
      t2[n].y = GATE4(t1[2*n].y, t1[2*n+1].y, c.x, c.y, c.z, c.w);
    }
    float2 t3[4];
    #pragma unroll
    for (int n = 0; n < 4; ++n) {
      float4 c = C[56 + n];
      t3[n].x = GATE4(t2[2*n].x, t2[2*n+1].x, c.x, c.y, c.z, c.w);
      t3[n].y = GATE4(t2[2*n].y, t2[2*n+1].y, c.x, c.y, c.z, c.w);
    }
    float2 t4[2];
    #pragma unroll
    for (int n = 0; n < 2; ++n) {
      float4 c = C[60 + n];
      t4[n].x = GATE4(t3[2*n].x, t3[2*n+1].x, c.x, c.y, c.z, c.w);
      t4[n].y = GATE4(t3[2*n].y, t3[2*n+1].y, c.x, c.y, c.z, c.w);
    }
    {
      float4 c = C[62];
      float2 r;
      r.x = GATE4(t4[0].x, t4[1].x, c.x, c.y, c.z, c.w);
      r.y = GATE4(t4[0].y, t4[1].y, c.x, c.y, c.z, c.w);
      *(float2*)outb = r;                        // 8B aligned (j even)
    }
    outb += 1024;                      // next tree: +32*32
  }
}

extern "C" void kernel_launch(void* const* d_in, const int* in_sizes, int n_in,
                              void* d_out, int out_size, void* d_ws, size_t ws_size,
                              hipStream_t stream) {
  const float* x = (const float*)d_in[0];
  Tabs tabs;
  for (int l = 0; l < 6; ++l) {
    tabs.ia[l] = (const int*)d_in[1 + 3 * l];
    tabs.ib[l] = (const int*)d_in[2 + 3 * l];
    tabs.w[l]  = (const float*)d_in[3 + 3 * l];
  }
  unsigned* tab = (unsigned*)d_ws;     // 64 trees * 288 dwords = 73.7 KB
  build_tree<<<16, 256, 0, stream>>>(tabs, tab);
  logic_conv<<<1024, 256, 0, stream>>>(x, tab, (float*)d_out);
}

// Round 8
// 30.754 us; speedup vs baseline: 3.5299x; 1.2229x over previous
//
#include <hip/hip_runtime.h>
#include <math.h>

// x: (32,32,32,32) f32; 6 layers, O=64 trees, gates/layer = 32,16,8,4,2,1
// out: (32,64,32,32) f32
//
// Fused-expansion formulation: the root gate's dependency cone expanded as a
// binary tree = 63 nodes (1+2+4+8+16+32). Precompute expanded coefs ->
// evaluation has ONLY static indices: t1[n] = gate(t0[2n], t0[2n+1]).
//
// d_ws layout (dwords), per tree o (288 dwords, 16B aligned):
//   tab[o*288 + 0..31]    packed leaf slab offsets (offa | offb<<16), L0 node n
//   tab[o*288 + 32..283]  float4 coefs, slots: L0 n->n, L1->32+n, L2->48+n,
//                         L3->56+n, L4->60+n, L5->62

struct Tabs { const int* ia[6]; const int* ib[6]; const float* w[6]; };

__device__ __constant__ float GM[64] = {
  0,0,0,0,   0,0,0,1,   0,1,0,-1,  0,1,0,0,
  0,0,1,-1,  0,0,1,0,   0,1,1,-2,  0,1,1,-1,
  1,-1,-1,1, 1,-1,-1,2, 1,0,-1,0,  1,0,-1,1,
  1,-1,0,0,  1,-1,0,1,  1,0,0,-1,  1,0,0,0 };

// y = c0 + c1*a + c2*b + c3*a*b  ==  fma(c2,b, fma(a, fma(c3,b,c1), c0))
#define GATE4(a, b, c0, c1, c2, c3) \
  fmaf((c2), (b), fmaf((a), fmaf((c3), (b), (c1)), (c0)))

// ---- builder: one thread per expanded node; walks its own root->node path ----
__global__ __launch_bounds__(256) void build_tree(Tabs t, unsigned* __restrict tab) {
  const int gid = blockIdx.x * 256 + threadIdx.x;     // [0, 4096)
  const int o = gid >> 6, slot = gid & 63;
  if (slot >= 63) return;
  int L, m;
  if      (slot < 32) { L = 0; m = slot;      }
  else if (slot < 48) { L = 1; m = slot - 32; }
  else if (slot < 56) { L = 2; m = slot - 48; }
  else if (slot < 60) { L = 3; m = slot - 56; }
  else if (slot < 62) { L = 4; m = slot - 60; }
  else                { L = 5; m = 0;         }
  const int dcnt[6] = {32, 16, 8, 4, 2, 1};
  const int d = 5 - L;                 // path length from root
  int g = 0;                           // gate id at current level (root = gate 0)
  for (int step = 0; step < d; ++step) {
    int lyr = 5 - step;
    int bit = (m >> (d - 1 - step)) & 1;
    g = (bit ? t.ib[lyr] : t.ia[lyr])[o * dcnt[lyr] + g];
  }

  // coefficients: softmax(w[L][o, g]) @ GATE_M
  const float4* wp = (const float4*)(t.w[L] + (o * dcnt[L] + g) * 16);
  float4 w0 = wp[0], w1 = wp[1], w2 = wp[2], w3 = wp[3];
  float wv[16] = { w0.x,w0.y,w0.z,w0.w, w1.x,w1.y,w1.z,w1.w,
                   w2.x,w2.y,w2.z,w2.w, w3.x,w3.y,w3.z,w3.w };
  float mx = -1e30f;
  #pragma unroll
  for (int k = 0; k < 16; ++k) mx = fmaxf(mx, wv[k]);
  float e[16], s = 0.f;
  #pragma unroll
  for (int k = 0; k < 16; ++k) { e[k] = expf(wv[k] - mx); s += e[k]; }
  float inv = 1.0f / s;
  float c0 = 0, c1 = 0, c2 = 0, c3 = 0;
  #pragma unroll
  for (int k = 0; k < 16; ++k) {
    float p = e[k] * inv;
    c0 += p * GM[k*4+0]; c1 += p * GM[k*4+1];
    c2 += p * GM[k*4+2]; c3 += p * GM[k*4+3];
  }
  float4* C = (float4*)(tab + o * 288 + 32);
  float4 c; c.x = c0; c.y = c1; c.z = c2; c.w = c3;
  C[slot] = c;

  if (L == 0) {
    // leaf slab offsets: feature f = ch*9 + ki*3 + kj -> xr[ch][6][34] offset
    int ia = t.ia[0][o * 32 + g], ib = t.ib[0][o * 32 + g];
    int ca = ia / 9, ra = ia - ca * 9, kia = ra / 3, kja = ra - kia * 3;
    int cb = ib / 9, rb = ib - cb * 9, kib = rb / 3, kjb = rb - kib * 3;
    unsigned offa = (unsigned)((ca * 6 + kia) * 34 + kja);
    unsigned offb = (unsigned)((cb * 6 + kib) * 34 + kjb);
    tab[o * 288 + slot] = offa | (offb << 16);
  }
}

// Block: 512 threads = 8 waves, all sharing one 4-row x 32-col tile.
// Each lane owns 2 adjacent columns (ds_read2_b32 leaf reads, dwordx2 stores,
// 2x ILP). Each wave evaluates 2 trees over the 128-px tile -> 8192 waves
// total = 32 waves/CU resident (grid 1024 = 4 blocks/CU x 8 waves).
// LDS slab 32ch x 6rows x 34cols = 25.5 KiB; 4 blocks/CU = 102 KiB.
// __launch_bounds__(512, 8): 8 waves/EU -> VGPR capped at 64.
// bid bits: [1:0]=treechunk(16 trees), [4:2]=rowchunk(4 rows), [9:5]=batch
__global__ __launch_bounds__(512, 8) void logic_conv(const float* __restrict x,
                                                     const unsigned* __restrict tab,
                                                     float* __restrict out) {
  __shared__ float xr[6528];                     // 32ch * 6rows * 34cols
  const int bid = blockIdx.x;
  const int tc = bid & 3, rc = (bid >> 2) & 7, b = bid >> 5;
  const int r0 = rc * 4;
  const int tid = threadIdx.x;

  // stage input slab: rows r0-1 .. r0+4, cols -1..32, zero-padded OOB
  for (int idx = tid; idx < 6528; idx += 512) {
    int c = idx / 204, rem = idx - c * 204;
    int rr = rem / 34, sc = rem - rr * 34;
    int gr = r0 - 1 + rr, gc = sc - 1;
    float v = 0.f;
    if ((unsigned)gr < 32u && (unsigned)gc < 32u)
      v = x[((b * 32 + c) * 32 + gr) * 32 + gc];
    xr[idx] = v;
  }
  __syncthreads();

  const int w = tid >> 6;              // wave id 0..7 -> tree pair
  const int lane = tid & 63;
  const int rbase = lane >> 4;         // 0..3 relative output row
  const int j = (lane & 15) * 2;       // 0,2,..,30 (col pair)
  const int lbase = rbase * 34 + j;
  const int o0 = tc * 16 + w * 2;      // first tree for this wave
  float* outb = out + ((b * 64 + o0) * 32 + (r0 + rbase)) * 32 + j;

  for (int t = 0; t < 2; ++t) {
    const int o = __builtin_amdgcn_readfirstlane(o0 + t);   // uniform -> s_load
    const unsigned* __restrict T = tab + o * 288;
    const float4*  __restrict C = (const float4*)(T + 32);

    // fused L0+L1: consume t0 pairs immediately (caps VGPR pressure ~50)
    float2 t1[16];
    #pragma unroll
    for (int n = 0; n < 16; ++n) {
      unsigned ipA = T[2*n], ipB = T[2*n+1];
      float4 cA = C[2*n], cB = C[2*n+1];
      int oa = (int)(ipA & 0xffffu) + lbase;
      int ob = (int)(ipA >> 16) + lbase;
      float a0 = xr[oa], a1 = xr[oa + 1];        // -> ds_read2_b32
      float b0 = xr[ob], b1 = xr[ob + 1];
      float ux = GATE4(a0, b0, cA.x, cA.y, cA.z, cA.w);
      float uy = GATE4(a1, b1, cA.x, cA.y, cA.z, cA.w);
      oa = (int)(ipB & 0xffffu) + lbase;
      ob = (int)(ipB >> 16) + lbase;
      float c0v = xr[oa], c1v = xr[oa + 1];
      float d0v = xr[ob], d1v = xr[ob + 1];
      float vx = GATE4(c0v, d0v, cB.x, cB.y, cB.z, cB.w);
      float vy = GATE4(c1v, d1v, cB.x, cB.y, cB.z, cB.w);
      float4 c1c = C[32 + n];
      t1[n].x = GATE4(ux, vx, c1c.x, c1c.y, c1c.z, c1c.w);
      t1[n].y = GATE4(uy, vy, c1c.x, c1c.y, c1c.z, c1c.w);
    }
    float2 t2[8];
    #pragma unroll
    for (int n = 0; n < 8; ++n) {
      float4 c = C[48 + n];
      t2[n].x = GATE4(t1[2*n].x, t1[2*n+1].x, c.x, c.y, c.z, c.w);
      t2[n].y = GATE4(t1[2*n].y, t1[2*n+1].y, c.x, c.y, c.z, c.w);
    }
    float2 t3[4];
    #pragma unroll
    for (int n = 0; n < 4; ++n) {
      float4 c = C[56 + n];
      t3[n].x = GATE4(t2[2*n].x, t2[2*n+1].x, c.x, c.y, c.z, c.w);
      t3[n].y = GATE4(t2[2*n].y, t2[2*n+1].y, c.x, c.y, c.z, c.w);
    }
    float2 t4[2];
    #pragma unroll
    for (int n = 0; n < 2; ++n) {
      float4 c = C[60 + n];
      t4[n].x = GATE4(t3[2*n].x, t3[2*n+1].x, c.x, c.y, c.z, c.w);
      t4[n].y = GATE4(t3[2*n].y, t3[2*n+1].y, c.x, c.y, c.z, c.w);
    }
    {
      float4 c = C[62];
      float2 r;
      r.x = GATE4(t4[0].x, t4[1].x, c.x, c.y, c.z, c.w);
      r.y = GATE4(t4[0].y, t4[1].y, c.x, c.y, c.z, c.w);
      *(float2*)outb = r;                        // 8B aligned (j even)
    }
    outb += 1024;                      // next tree: +32*32
  }
}

extern "C" void kernel_launch(void* const* d_in, const int* in_sizes, int n_in,
                              void* d_out, int out_size, void* d_ws, size_t ws_size,
                              hipStream_t stream) {
  const float* x = (const float*)d_in[0];
  Tabs tabs;
  for (int l = 0; l < 6; ++l) {
    tabs.ia[l] = (const int*)d_in[1 + 3 * l];
    tabs.ib[l] = (const int*)d_in[2 + 3 * l];
    tabs.w[l]  = (const float*)d_in[3 + 3 * l];
  }
  unsigned* tab = (unsigned*)d_ws;     // 64 trees * 288 dwords = 73.7 KB
  build_tree<<<16, 256, 0, stream>>>(tabs, tab);
  logic_conv<<<1024, 512, 0, stream>>>(x, tab, (float*)d_out);
}

// Round 9
// 28.813 us; speedup vs baseline: 3.7677x; 1.0674x over previous
//
#include <hip/hip_runtime.h>
#include <math.h>

// x: (32,32,32,32) f32; 6 layers, O=64 trees, gates/layer = 32,16,8,4,2,1
// out: (32,64,32,32) f32
//
// Fused-expansion formulation: the root gate's dependency cone expanded as a
// binary tree = 63 nodes (1+2+4+8+16+32). Precompute expanded coefs ->
// evaluation has ONLY static indices: t1[n] = gate(t0[2n], t0[2n+1]).
//
// d_ws layout (dwords), per tree o (288 dwords, 16B aligned):
//   tab[o*288 + 0..31]    packed leaf slab offsets (offa | offb<<16), L0 node n
//   tab[o*288 + 32..283]  float4 coefs, slots: L0 n->n, L1->32+n, L2->48+n,
//                         L3->56+n, L4->60+n, L5->62
// Slab geometry: xr[ch][6][35] (35-dword row stride), lane adds rbase*35 + j.

struct Tabs { const int* ia[6]; const int* ib[6]; const float* w[6]; };

__device__ __constant__ float GM[64] = {
  0,0,0,0,   0,0,0,1,   0,1,0,-1,  0,1,0,0,
  0,0,1,-1,  0,0,1,0,   0,1,1,-2,  0,1,1,-1,
  1,-1,-1,1, 1,-1,-1,2, 1,0,-1,0,  1,0,-1,1,
  1,-1,0,0,  1,-1,0,1,  1,0,0,-1,  1,0,0,0 };

typedef float v2f __attribute__((ext_vector_type(2)));

// packed gate: y = c0 + c1*a + c2*b + c3*a*b, evaluated on both pixels at once
// = fma(c2,b, fma(a, fma(c3,b,c1), c0))  -> 3x v_pk_fma_f32
__device__ __forceinline__ v2f gatep(v2f a, v2f b, float4 c) {
  v2f t = __builtin_elementwise_fma((v2f)c.w, b, (v2f)c.y);
  t = __builtin_elementwise_fma(a, t, (v2f)c.x);
  return __builtin_elementwise_fma((v2f)c.z, b, t);
}

// ---- builder: one thread per expanded node; walks its own root->node path ----
__global__ __launch_bounds__(256) void build_tree(Tabs t, unsigned* __restrict tab) {
  const int gid = blockIdx.x * 256 + threadIdx.x;     // [0, 4096)
  const int o = gid >> 6, slot = gid & 63;
  if (slot >= 63) return;
  int L, m;
  if      (slot < 32) { L = 0; m = slot;      }
  else if (slot < 48) { L = 1; m = slot - 32; }
  else if (slot < 56) { L = 2; m = slot - 48; }
  else if (slot < 60) { L = 3; m = slot - 56; }
  else if (slot < 62) { L = 4; m = slot - 60; }
  else                { L = 5; m = 0;         }
  const int dcnt[6] = {32, 16, 8, 4, 2, 1};
  const int d = 5 - L;                 // path length from root
  int g = 0;                           // gate id at current level (root = gate 0)
  for (int step = 0; step < d; ++step) {
    int lyr = 5 - step;
    int bit = (m >> (d - 1 - step)) & 1;
    g = (bit ? t.ib[lyr] : t.ia[lyr])[o * dcnt[lyr] + g];
  }

  // coefficients: softmax(w[L][o, g]) @ GATE_M
  const float4* wp = (const float4*)(t.w[L] + (o * dcnt[L] + g) * 16);
  float4 w0 = wp[0], w1 = wp[1], w2 = wp[2], w3 = wp[3];
  float wv[16] = { w0.x,w0.y,w0.z,w0.w, w1.x,w1.y,w1.z,w1.w,
                   w2.x,w2.y,w2.z,w2.w, w3.x,w3.y,w3.z,w3.w };
  float mx = -1e30f;
  #pragma unroll
  for (int k = 0; k < 16; ++k) mx = fmaxf(mx, wv[k]);
  float e[16], s = 0.f;
  #pragma unroll
  for (int k = 0; k < 16; ++k) { e[k] = expf(wv[k] - mx); s += e[k]; }
  float inv = 1.0f / s;
  float c0 = 0, c1 = 0, c2 = 0, c3 = 0;
  #pragma unroll
  for (int k = 0; k < 16; ++k) {
    float p = e[k] * inv;
    c0 += p * GM[k*4+0]; c1 += p * GM[k*4+1];
    c2 += p * GM[k*4+2]; c3 += p * GM[k*4+3];
  }
  float4* C = (float4*)(tab + o * 288 + 32);
  float4 c; c.x = c0; c.y = c1; c.z = c2; c.w = c3;
  C[slot] = c;

  if (L == 0) {
    // leaf slab offsets: feature f = ch*9 + ki*3 + kj -> xr[ch][6][35] offset
    int ia = t.ia[0][o * 32 + g], ib = t.ib[0][o * 32 + g];
    int ca = ia / 9, ra = ia - ca * 9, kia = ra / 3, kja = ra - kia * 3;
    int cb = ib / 9, rb = ib - cb * 9, kib = rb / 3, kjb = rb - kib * 3;
    unsigned offa = (unsigned)((ca * 6 + kia) * 35 + kja);
    unsigned offb = (unsigned)((cb * 6 + kib) * 35 + kjb);
    tab[o * 288 + slot] = offa | (offb << 16);
  }
}

// Block: 512 threads = 8 waves, all sharing one 4-row x 32-col tile.
// Each lane owns 2 adjacent columns (ds_read2_b32 leaf reads, dwordx2 stores,
// pk_fma 2x-packed gate math). Each wave evaluates 2 trees -> 8192 waves
// total = 32 waves/CU resident (grid 1024 = 4 blocks/CU x 8 waves).
// LDS slab 32ch x 6rows x 35 = 26.25 KiB; 4 blocks/CU = 105 KiB.
// bid bits: [1:0]=treechunk(16 trees), [4:2]=rowchunk(4 rows), [9:5]=batch
__global__ __launch_bounds__(512, 8) void logic_conv(const float* __restrict x,
                                                     const unsigned* __restrict tab,
                                                     float* __restrict out) {
  __shared__ float xr[6720];                     // 32ch * 6rows * 35
  const int bid = blockIdx.x;
  const int tc = bid & 3, rc = (bid >> 2) & 7, b = bid >> 5;
  const int r0 = rc * 4;
  const int tid = threadIdx.x;

  // stage input slab: rows r0-1 .. r0+4, cols -1..32 (+1 pad), zero OOB
  for (int idx = tid; idx < 6720; idx += 512) {
    int c = idx / 210, rem = idx - c * 210;
    int rr = rem / 35, sc = rem - rr * 35;
    int gr = r0 - 1 + rr, gc = sc - 1;
    float v = 0.f;
    if ((unsigned)gr < 32u && (unsigned)gc < 32u)
      v = x[((b * 32 + c) * 32 + gr) * 32 + gc];
    xr[idx] = v;
  }
  __syncthreads();

  const int w = tid >> 6;              // wave id 0..7 -> tree pair
  const int lane = tid & 63;
  const int rbase = lane >> 4;         // 0..3 relative output row
  const int j = (lane & 15) * 2;       // 0,2,..,30 (col pair)
  const int lbase = rbase * 35 + j;
  const int o0 = tc * 16 + w * 2;      // first tree for this wave
  float* outb = out + ((b * 64 + o0) * 32 + (r0 + rbase)) * 32 + j;

  for (int t = 0; t < 2; ++t) {
    const int o = __builtin_amdgcn_readfirstlane(o0 + t);   // uniform -> s_load
    const unsigned* __restrict T = tab + o * 288;
    const float4*  __restrict C = (const float4*)(T + 32);

    // fused L0+L1: consume leaf pairs immediately (caps VGPR pressure)
    v2f t1[16];
    #pragma unroll
    for (int n = 0; n < 16; ++n) {
      unsigned ipA = T[2*n], ipB = T[2*n+1];
      int oa = (int)(ipA & 0xffffu) + lbase;
      int ob = (int)(ipA >> 16) + lbase;
      v2f a, bb;
      a.x = xr[oa]; a.y = xr[oa + 1];            // -> ds_read2_b32
      bb.x = xr[ob]; bb.y = xr[ob + 1];
      v2f u = gatep(a, bb, C[2*n]);
      oa = (int)(ipB & 0xffffu) + lbase;
      ob = (int)(ipB >> 16) + lbase;
      v2f cc, dd;
      cc.x = xr[oa]; cc.y = xr[oa + 1];
      dd.x = xr[ob]; dd.y = xr[ob + 1];
      v2f v = gatep(cc, dd, C[2*n+1]);
      t1[n] = gatep(u, v, C[32 + n]);
    }
    v2f t2[8];
    #pragma unroll
    for (int n = 0; n < 8; ++n) t2[n] = gatep(t1[2*n], t1[2*n+1], C[48 + n]);
    v2f t3[4];
    #pragma unroll
    for (int n = 0; n < 4; ++n) t3[n] = gatep(t2[2*n], t2[2*n+1], C[56 + n]);
    v2f t4[2];
    #pragma unroll
    for (int n = 0; n < 2; ++n) t4[n] = gatep(t3[2*n], t3[2*n+1], C[60 + n]);
    {
      v2f r = gatep(t4[0], t4[1], C[62]);
      float2 rr; rr.x = r.x; rr.y = r.y;
      *(float2*)outb = rr;                       // 8B aligned (j even)
    }
    outb += 1024;                      // next tree: +32*32
  }
}

extern "C" void kernel_launch(void* const* d_in, const int* in_sizes, int n_in,
                              void* d_out, int out_size, void* d_ws, size_t ws_size,
                              hipStream_t stream) {
  const float* x = (const float*)d_in[0];
  Tabs tabs;
  for (int l = 0; l < 6; ++l) {
    tabs.ia[l] = (const int*)d_in[1 + 3 * l];
    tabs.ib[l] = (const int*)d_in[2 + 3 * l];
    tabs.w[l]  = (const float*)d_in[3 + 3 * l];
  }
  unsigned* tab = (unsigned*)d_ws;     // 64 trees * 288 dwords = 73.7 KB
  build_tree<<<16, 256, 0, stream>>>(tabs, tab);
  logic_conv<<<1024, 512, 0, stream>>>(x, tab, (float*)d_out);
}